// Round 1
// baseline (2634.814 us; speedup 1.0000x reference)
//
#include <hip/hip_runtime.h>
#include <cstdint>

constexpr int Bn = 128;
constexpr int Tn = 1024;
constexpr int Dn = 64;
constexpr int Hn = 256;   // H1 == H2 == 256
constexpr int On = 128;

__device__ __forceinline__ float fast_tanh(float x) {
  // tanh(x) = 1 - 2/(exp(2x)+1); exact at both saturated ends, ~1e-7 rel err.
  float e = __expf(2.0f * x);
  return 1.0f - 2.0f / (e + 1.0f);
}

// ---------------------------------------------------------------------------
// Phase 1: per-batch layer-1 scan. One WG per batch element (128 WGs).
// 512 threads: thread (p = tid>>8, j = tid&255) holds Wh1[p*128 .. p*128+127][j]
// and Wx1[p*32 .. p*32+31][j] in VGPRs. h broadcast from LDS (free broadcast).
// h1_t = tanh(x_t@Wx1 + h1_{t-1}@Wh1 + b1); writes all h1_t to global.
// ---------------------------------------------------------------------------
__global__ __launch_bounds__(512) void scan1_kernel(
    const float* __restrict__ x,    // [B,T,64]
    const float* __restrict__ Wx1,  // [64,256]
    const float* __restrict__ Wh1,  // [256,256]
    const float* __restrict__ b1,   // [256]
    float* __restrict__ h1out) {    // [B,T,256]
  __shared__ alignas(16) float hbuf[2][Hn];
  __shared__ alignas(16) float xbuf[2][Dn];
  __shared__ float part[512];
  const int tid = threadIdx.x;
  const int j = tid & 255;
  const int p = tid >> 8;  // K-half
  const int b = blockIdx.x;
  const float* xb = x + (size_t)b * Tn * Dn;
  float* hb = h1out + (size_t)b * Tn * Hn;

  float wh[128];
  {
    const float* Wp = Wh1 + (size_t)(p * 128) * Hn + j;
    #pragma unroll
    for (int k = 0; k < 128; ++k) wh[k] = Wp[(size_t)k * Hn];
  }
  float wx[32];
  {
    const float* Wp = Wx1 + (size_t)(p * 32) * Hn + j;
    #pragma unroll
    for (int k = 0; k < 32; ++k) wx[k] = Wp[(size_t)k * Hn];
  }
  const float bias = b1[j];

  if (tid < Hn) hbuf[0][tid] = 0.0f;
  if (tid < Dn) xbuf[0][tid] = xb[tid];  // x_0
  __syncthreads();

  int cur = 0;
  for (int t = 0; t < Tn; ++t) {
    // stage x_{t+1} early (consumed next iteration; end-of-iter barrier covers it)
    if (tid < Dn && t + 1 < Tn) xbuf[cur ^ 1][tid] = xb[(size_t)(t + 1) * Dn + tid];

    float a0 = 0.f, a1 = 0.f, a2 = 0.f, a3 = 0.f;
    const float4* h4 = (const float4*)&hbuf[cur][p * 128];
    #pragma unroll
    for (int q = 0; q < 32; ++q) {
      float4 hv = h4[q];
      a0 = fmaf(hv.x, wh[4 * q + 0], a0);
      a1 = fmaf(hv.y, wh[4 * q + 1], a1);
      a2 = fmaf(hv.z, wh[4 * q + 2], a2);
      a3 = fmaf(hv.w, wh[4 * q + 3], a3);
    }
    const float4* x4 = (const float4*)&xbuf[cur][p * 32];
    #pragma unroll
    for (int q = 0; q < 8; ++q) {
      float4 xv = x4[q];
      a0 = fmaf(xv.x, wx[4 * q + 0], a0);
      a1 = fmaf(xv.y, wx[4 * q + 1], a1);
      a2 = fmaf(xv.z, wx[4 * q + 2], a2);
      a3 = fmaf(xv.w, wx[4 * q + 3], a3);
    }
    part[tid] = (a0 + a1) + (a2 + a3);
    __syncthreads();
    if (tid < Hn) {
      float s = part[j] + part[Hn + j] + bias;
      float h = fast_tanh(s);
      hbuf[cur ^ 1][j] = h;
      hb[(size_t)t * Hn + j] = h;
    }
    cur ^= 1;
    __syncthreads();
  }
}

// ---------------------------------------------------------------------------
// Phase 2: u2 = h1 @ Wx2 + b2.  M=131072, N=K=256.  WG = 64 rows x 256 cols.
// In-place safe: each WG finishes all reads of its 64 rows before epilogue.
// ---------------------------------------------------------------------------
__global__ __launch_bounds__(256) void gemm256_kernel(
    const float* A,                 // [M,256] (may alias out)
    const float* __restrict__ W,    // [256,256]
    const float* __restrict__ bias, // [256]
    float* out,                     // [M,256]
    int M) {
  __shared__ alignas(16) float At[64][64];  // 16 KB
  const int j = threadIdx.x;
  const int m0 = blockIdx.x * 64;
  float acc[64];
  #pragma unroll
  for (int m = 0; m < 64; ++m) acc[m] = 0.f;

  for (int kc = 0; kc < 256; kc += 64) {
    __syncthreads();  // protect previous chunk's LDS reads
    {
      const int flat = j * 16;
      const int row = flat >> 6;
      const int kk = flat & 63;  // 0/16/32/48 -> 16B aligned
      const float* src = A + (size_t)(m0 + row) * 256 + kc + kk;
      float4 v0 = ((const float4*)src)[0];
      float4 v1 = ((const float4*)src)[1];
      float4 v2 = ((const float4*)src)[2];
      float4 v3 = ((const float4*)src)[3];
      *(float4*)&At[row][kk + 0] = v0;
      *(float4*)&At[row][kk + 4] = v1;
      *(float4*)&At[row][kk + 8] = v2;
      *(float4*)&At[row][kk + 12] = v3;
    }
    __syncthreads();
    const float* Wp = W + (size_t)kc * 256 + j;
    for (int kq = 0; kq < 16; ++kq) {
      float w0 = Wp[(size_t)(4 * kq + 0) * 256];
      float w1 = Wp[(size_t)(4 * kq + 1) * 256];
      float w2 = Wp[(size_t)(4 * kq + 2) * 256];
      float w3 = Wp[(size_t)(4 * kq + 3) * 256];
      #pragma unroll
      for (int m = 0; m < 64; ++m) {
        float4 a = *(const float4*)&At[m][4 * kq];  // broadcast read, conflict-free
        acc[m] = fmaf(a.x, w0, acc[m]);
        acc[m] = fmaf(a.y, w1, acc[m]);
        acc[m] = fmaf(a.z, w2, acc[m]);
        acc[m] = fmaf(a.w, w3, acc[m]);
      }
    }
  }
  const float bj = bias[j];
  #pragma unroll
  for (int m = 0; m < 64; ++m)
    out[(size_t)(m0 + m) * 256 + j] = acc[m] + bj;
}

// ---------------------------------------------------------------------------
// Phase 3: per-batch layer-2 scan. h2_t = tanh(u2_t + h2_{t-1}@Wh2).
// u2 prefetched one step ahead into registers. Only final h2 kept.
// ---------------------------------------------------------------------------
__global__ __launch_bounds__(512) void scan2_kernel(
    const float* __restrict__ U,    // [B,T,256] = h1@Wx2 + b2
    const float* __restrict__ Wh2,  // [256,256]
    float* __restrict__ hfinal) {   // [B,256]
  __shared__ alignas(16) float hbuf[2][Hn];
  __shared__ float part[512];
  const int tid = threadIdx.x;
  const int j = tid & 255;
  const int p = tid >> 8;
  const int b = blockIdx.x;
  const float* Ub = U + (size_t)b * Tn * Hn;

  float wh[128];
  {
    const float* Wp = Wh2 + (size_t)(p * 128) * Hn + j;
    #pragma unroll
    for (int k = 0; k < 128; ++k) wh[k] = Wp[(size_t)k * Hn];
  }
  if (tid < Hn) hbuf[0][tid] = 0.0f;
  __syncthreads();

  float ucur = (tid < Hn) ? Ub[j] : 0.f;
  int cur = 0;
  for (int t = 0; t < Tn; ++t) {
    float unext = 0.f;
    if (tid < Hn && t + 1 < Tn) unext = Ub[(size_t)(t + 1) * Hn + j];  // prefetch

    float a0 = 0.f, a1 = 0.f, a2 = 0.f, a3 = 0.f;
    const float4* h4 = (const float4*)&hbuf[cur][p * 128];
    #pragma unroll
    for (int q = 0; q < 32; ++q) {
      float4 hv = h4[q];
      a0 = fmaf(hv.x, wh[4 * q + 0], a0);
      a1 = fmaf(hv.y, wh[4 * q + 1], a1);
      a2 = fmaf(hv.z, wh[4 * q + 2], a2);
      a3 = fmaf(hv.w, wh[4 * q + 3], a3);
    }
    part[tid] = (a0 + a1) + (a2 + a3);
    __syncthreads();
    if (tid < Hn) {
      float h = fast_tanh(part[j] + part[Hn + j] + ucur);
      hbuf[cur ^ 1][j] = h;
    }
    ucur = unext;
    cur ^= 1;
    __syncthreads();
  }
  if (tid < Hn) hfinal[(size_t)b * Hn + tid] = hbuf[cur][tid];
}

// ---------------------------------------------------------------------------
// Phase 4: out = softmax(h2_T @ Wd + bd). One WG (128 thr) per batch row.
// ---------------------------------------------------------------------------
__global__ __launch_bounds__(128) void head_kernel(
    const float* __restrict__ hfinal,  // [B,256]
    const float* __restrict__ Wd,      // [256,128]
    const float* __restrict__ bd,      // [128]
    float* __restrict__ out) {         // [B,128]
  __shared__ float hrow[Hn];
  __shared__ float red[On];
  const int o = threadIdx.x;
  const int b = blockIdx.x;
  hrow[o] = hfinal[(size_t)b * Hn + o];
  hrow[o + 128] = hfinal[(size_t)b * Hn + 128 + o];
  __syncthreads();
  float acc = bd[o];
  #pragma unroll 8
  for (int k = 0; k < Hn; ++k) acc = fmaf(hrow[k], Wd[(size_t)k * On + o], acc);
  red[o] = acc;
  __syncthreads();
  #pragma unroll
  for (int s = 64; s > 0; s >>= 1) {
    if (o < s) red[o] = fmaxf(red[o], red[o + s]);
    __syncthreads();
  }
  const float mx = red[0];
  __syncthreads();
  const float e = __expf(acc - mx);
  red[o] = e;
  __syncthreads();
  #pragma unroll
  for (int s = 64; s > 0; s >>= 1) {
    if (o < s) red[o] += red[o + s];
    __syncthreads();
  }
  out[(size_t)b * On + o] = e / red[0];
}

// ---------------------------------------------------------------------------
extern "C" void kernel_launch(void* const* d_in, const int* in_sizes, int n_in,
                              void* d_out, int out_size, void* d_ws, size_t ws_size,
                              hipStream_t stream) {
  const float* x   = (const float*)d_in[0];
  const float* Wx1 = (const float*)d_in[1];
  const float* Wh1 = (const float*)d_in[2];
  const float* b1  = (const float*)d_in[3];
  const float* Wx2 = (const float*)d_in[4];
  const float* Wh2 = (const float*)d_in[5];
  const float* b2  = (const float*)d_in[6];
  const float* Wd  = (const float*)d_in[7];
  const float* bd  = (const float*)d_in[8];
  float* out = (float*)d_out;

  // Workspace: one [B*T*256] f32 buffer (h1, overwritten in place by u2) + h2 final.
  // Needs 128 MiB + 128 KiB of d_ws.
  float* buf = (float*)d_ws;
  float* hfinal = buf + (size_t)Bn * Tn * Hn;

  scan1_kernel<<<Bn, 512, 0, stream>>>(x, Wx1, Wh1, b1, buf);
  gemm256_kernel<<<(Bn * Tn) / 64, 256, 0, stream>>>(buf, Wx2, b2, buf, Bn * Tn);
  scan2_kernel<<<Bn, 512, 0, stream>>>(buf, Wh2, hfinal);
  head_kernel<<<Bn, 128, 0, stream>>>(hfinal, Wd, bd, out);
}

// Round 2
// 2527.478 us; speedup vs baseline: 1.0425x; 1.0425x over previous
//
#include <hip/hip_runtime.h>
#include <cstdint>

constexpr int Bn = 128;
constexpr int Tn = 1024;
constexpr int Dn = 64;
constexpr int Hn = 256;   // H1 == H2 == 256
constexpr int On = 128;

typedef float v2f __attribute__((ext_vector_type(2)));

__device__ __forceinline__ float fast_tanh(float x) {
  // tanh(x) = 1 - 2/(exp(2x)+1); exact at both saturated ends, ~1e-7 rel err.
  float e = __expf(2.0f * x);
  return 1.0f - 2.0f / (e + 1.0f);
}

// ---------------------------------------------------------------------------
// Phase 1: per-batch layer-1 scan. One WG (512 thr) per batch element.
// Thread (c0 = tid>>3, ks = tid&7): computes columns [4c0,4c0+4) over K-slice
// ks (32 Wh-rows + 8 Wx-rows). Weights live in VGPRs as k-paired float2 so the
// inner loop is v_pk_fma_f32 (2 MAC/instr). h operands are reused 4x per LDS
// read (C=4 column blocking) -> LDS delivery 82 KB/step vs 327 KB in R1.
// The 8 K-partials per column sit in 8 consecutive lanes of one wave ->
// butterfly shfl_xor reduction, no LDS partials, ONE barrier per step.
// ---------------------------------------------------------------------------
__global__ __launch_bounds__(512) void scan1_kernel(
    const float* __restrict__ x,    // [B,T,64]
    const float* __restrict__ Wx1,  // [64,256]
    const float* __restrict__ Wh1,  // [256,256]
    const float* __restrict__ b1,   // [256]
    float* __restrict__ h1out) {    // [B,T,256]
  __shared__ alignas(16) float hbuf[2][Hn];
  __shared__ alignas(16) float xbuf[2][Dn];
  const int tid = threadIdx.x;
  const int c0 = tid >> 3;  // column group [4c0, 4c0+4)
  const int ks = tid & 7;   // K-slice
  const int b = blockIdx.x;
  const float* xb = x + (size_t)b * Tn * Dn;
  float* hb = h1out + (size_t)b * Tn * Hn;

  // Wh1 rows [ks*32, ks*32+32), k-paired: whp[q][c] = {Wh[2q][c], Wh[2q+1][c]}
  v2f whp[16][4];
  #pragma unroll
  for (int q = 0; q < 16; ++q) {
    const float* r0 = Wh1 + (size_t)(ks * 32 + 2 * q) * Hn + 4 * c0;
    float4 a = *(const float4*)r0;
    float4 bb = *(const float4*)(r0 + Hn);
    whp[q][0] = (v2f){a.x, bb.x};
    whp[q][1] = (v2f){a.y, bb.y};
    whp[q][2] = (v2f){a.z, bb.z};
    whp[q][3] = (v2f){a.w, bb.w};
  }
  // Wx1 rows [ks*8, ks*8+8)
  v2f wxp[4][4];
  #pragma unroll
  for (int q = 0; q < 4; ++q) {
    const float* r0 = Wx1 + (size_t)(ks * 8 + 2 * q) * Hn + 4 * c0;
    float4 a = *(const float4*)r0;
    float4 bb = *(const float4*)(r0 + Hn);
    wxp[q][0] = (v2f){a.x, bb.x};
    wxp[q][1] = (v2f){a.y, bb.y};
    wxp[q][2] = (v2f){a.z, bb.z};
    wxp[q][3] = (v2f){a.w, bb.w};
  }
  const float4 bias = *(const float4*)(b1 + 4 * c0);

  if (tid < 64) *(float4*)&hbuf[0][4 * tid] = make_float4(0.f, 0.f, 0.f, 0.f);
  if (tid < 16) *(float4*)&xbuf[0][4 * tid] = *(const float4*)(xb + 4 * tid);
  __syncthreads();

  int cur = 0;
  for (int t = 0; t < Tn; ++t) {
    // stage x_{t+1}; consumed after the end-of-iter barrier
    if (tid < 16 && t + 1 < Tn)
      *(float4*)&xbuf[cur ^ 1][4 * tid] =
          *(const float4*)(xb + (size_t)(t + 1) * Dn + 4 * tid);

    v2f a0 = (v2f){0.f, 0.f}, a1 = a0, a2 = a0, a3 = a0;
    const float4* h4 = (const float4*)&hbuf[cur][ks * 32];
    #pragma unroll
    for (int qq = 0; qq < 8; ++qq) {
      float4 hv = h4[qq];
      v2f hA = (v2f){hv.x, hv.y};
      v2f hB = (v2f){hv.z, hv.w};
      a0 = __builtin_elementwise_fma(hA, whp[2 * qq][0], a0);
      a1 = __builtin_elementwise_fma(hA, whp[2 * qq][1], a1);
      a2 = __builtin_elementwise_fma(hA, whp[2 * qq][2], a2);
      a3 = __builtin_elementwise_fma(hA, whp[2 * qq][3], a3);
      a0 = __builtin_elementwise_fma(hB, whp[2 * qq + 1][0], a0);
      a1 = __builtin_elementwise_fma(hB, whp[2 * qq + 1][1], a1);
      a2 = __builtin_elementwise_fma(hB, whp[2 * qq + 1][2], a2);
      a3 = __builtin_elementwise_fma(hB, whp[2 * qq + 1][3], a3);
    }
    const float4* x4 = (const float4*)&xbuf[cur][ks * 8];
    #pragma unroll
    for (int qq = 0; qq < 2; ++qq) {
      float4 xv = x4[qq];
      v2f xA = (v2f){xv.x, xv.y};
      v2f xB = (v2f){xv.z, xv.w};
      a0 = __builtin_elementwise_fma(xA, wxp[2 * qq][0], a0);
      a1 = __builtin_elementwise_fma(xA, wxp[2 * qq][1], a1);
      a2 = __builtin_elementwise_fma(xA, wxp[2 * qq][2], a2);
      a3 = __builtin_elementwise_fma(xA, wxp[2 * qq][3], a3);
      a0 = __builtin_elementwise_fma(xB, wxp[2 * qq + 1][0], a0);
      a1 = __builtin_elementwise_fma(xB, wxp[2 * qq + 1][1], a1);
      a2 = __builtin_elementwise_fma(xB, wxp[2 * qq + 1][2], a2);
      a3 = __builtin_elementwise_fma(xB, wxp[2 * qq + 1][3], a3);
    }
    float s0 = a0.x + a0.y;
    float s1 = a1.x + a1.y;
    float s2 = a2.x + a2.y;
    float s3 = a3.x + a3.y;
    #pragma unroll
    for (int d = 1; d < 8; d <<= 1) {
      s0 += __shfl_xor(s0, d, 64);
      s1 += __shfl_xor(s1, d, 64);
      s2 += __shfl_xor(s2, d, 64);
      s3 += __shfl_xor(s3, d, 64);
    }
    if (ks == 0) {
      float4 h;
      h.x = fast_tanh(s0 + bias.x);
      h.y = fast_tanh(s1 + bias.y);
      h.z = fast_tanh(s2 + bias.z);
      h.w = fast_tanh(s3 + bias.w);
      *(float4*)&hbuf[cur ^ 1][4 * c0] = h;
      *(float4*)(hb + (size_t)t * Hn + 4 * c0) = h;
    }
    cur ^= 1;
    __syncthreads();  // single barrier: double-buffered hbuf/xbuf
  }
}

// ---------------------------------------------------------------------------
// Phase 2: u2 = h1 @ Wx2 + b2.  M=131072, N=K=256.  WG = 64 rows x 256 cols.
// In-place safe: each WG finishes all reads of its 64 rows before epilogue.
// ---------------------------------------------------------------------------
__global__ __launch_bounds__(256) void gemm256_kernel(
    const float* A,                 // [M,256] (may alias out)
    const float* __restrict__ W,    // [256,256]
    const float* __restrict__ bias, // [256]
    float* out,                     // [M,256]
    int M) {
  __shared__ alignas(16) float At[64][64];  // 16 KB
  const int j = threadIdx.x;
  const int m0 = blockIdx.x * 64;
  float acc[64];
  #pragma unroll
  for (int m = 0; m < 64; ++m) acc[m] = 0.f;

  for (int kc = 0; kc < 256; kc += 64) {
    __syncthreads();  // protect previous chunk's LDS reads
    {
      const int flat = j * 16;
      const int row = flat >> 6;
      const int kk = flat & 63;
      const float* src = A + (size_t)(m0 + row) * 256 + kc + kk;
      float4 v0 = ((const float4*)src)[0];
      float4 v1 = ((const float4*)src)[1];
      float4 v2 = ((const float4*)src)[2];
      float4 v3 = ((const float4*)src)[3];
      *(float4*)&At[row][kk + 0] = v0;
      *(float4*)&At[row][kk + 4] = v1;
      *(float4*)&At[row][kk + 8] = v2;
      *(float4*)&At[row][kk + 12] = v3;
    }
    __syncthreads();
    const float* Wp = W + (size_t)kc * 256 + j;
    for (int kq = 0; kq < 16; ++kq) {
      float w0 = Wp[(size_t)(4 * kq + 0) * 256];
      float w1 = Wp[(size_t)(4 * kq + 1) * 256];
      float w2 = Wp[(size_t)(4 * kq + 2) * 256];
      float w3 = Wp[(size_t)(4 * kq + 3) * 256];
      #pragma unroll
      for (int m = 0; m < 64; ++m) {
        float4 a = *(const float4*)&At[m][4 * kq];  // broadcast read
        acc[m] = fmaf(a.x, w0, acc[m]);
        acc[m] = fmaf(a.y, w1, acc[m]);
        acc[m] = fmaf(a.z, w2, acc[m]);
        acc[m] = fmaf(a.w, w3, acc[m]);
      }
    }
  }
  const float bj = bias[j];
  #pragma unroll
  for (int m = 0; m < 64; ++m)
    out[(size_t)(m0 + m) * 256 + j] = acc[m] + bj;
}

// ---------------------------------------------------------------------------
// Phase 3: per-batch layer-2 scan, same structure as scan1 (K=256 only).
// u2_t prefetched one step ahead into registers by the ks==0 lanes.
// ---------------------------------------------------------------------------
__global__ __launch_bounds__(512) void scan2_kernel(
    const float* __restrict__ U,    // [B,T,256] = h1@Wx2 + b2
    const float* __restrict__ Wh2,  // [256,256]
    float* __restrict__ hfinal) {   // [B,256]
  __shared__ alignas(16) float hbuf[2][Hn];
  const int tid = threadIdx.x;
  const int c0 = tid >> 3;
  const int ks = tid & 7;
  const int b = blockIdx.x;
  const float* Ub = U + (size_t)b * Tn * Hn;

  v2f whp[16][4];
  #pragma unroll
  for (int q = 0; q < 16; ++q) {
    const float* r0 = Wh2 + (size_t)(ks * 32 + 2 * q) * Hn + 4 * c0;
    float4 a = *(const float4*)r0;
    float4 bb = *(const float4*)(r0 + Hn);
    whp[q][0] = (v2f){a.x, bb.x};
    whp[q][1] = (v2f){a.y, bb.y};
    whp[q][2] = (v2f){a.z, bb.z};
    whp[q][3] = (v2f){a.w, bb.w};
  }

  if (tid < 64) *(float4*)&hbuf[0][4 * tid] = make_float4(0.f, 0.f, 0.f, 0.f);
  __syncthreads();

  float4 ucur = make_float4(0.f, 0.f, 0.f, 0.f);
  if (ks == 0) ucur = *(const float4*)(Ub + 4 * c0);

  int cur = 0;
  for (int t = 0; t < Tn; ++t) {
    float4 unext = make_float4(0.f, 0.f, 0.f, 0.f);
    if (ks == 0 && t + 1 < Tn)
      unext = *(const float4*)(Ub + (size_t)(t + 1) * Hn + 4 * c0);  // prefetch

    v2f a0 = (v2f){0.f, 0.f}, a1 = a0, a2 = a0, a3 = a0;
    const float4* h4 = (const float4*)&hbuf[cur][ks * 32];
    #pragma unroll
    for (int qq = 0; qq < 8; ++qq) {
      float4 hv = h4[qq];
      v2f hA = (v2f){hv.x, hv.y};
      v2f hB = (v2f){hv.z, hv.w};
      a0 = __builtin_elementwise_fma(hA, whp[2 * qq][0], a0);
      a1 = __builtin_elementwise_fma(hA, whp[2 * qq][1], a1);
      a2 = __builtin_elementwise_fma(hA, whp[2 * qq][2], a2);
      a3 = __builtin_elementwise_fma(hA, whp[2 * qq][3], a3);
      a0 = __builtin_elementwise_fma(hB, whp[2 * qq + 1][0], a0);
      a1 = __builtin_elementwise_fma(hB, whp[2 * qq + 1][1], a1);
      a2 = __builtin_elementwise_fma(hB, whp[2 * qq + 1][2], a2);
      a3 = __builtin_elementwise_fma(hB, whp[2 * qq + 1][3], a3);
    }
    float s0 = a0.x + a0.y;
    float s1 = a1.x + a1.y;
    float s2 = a2.x + a2.y;
    float s3 = a3.x + a3.y;
    #pragma unroll
    for (int d = 1; d < 8; d <<= 1) {
      s0 += __shfl_xor(s0, d, 64);
      s1 += __shfl_xor(s1, d, 64);
      s2 += __shfl_xor(s2, d, 64);
      s3 += __shfl_xor(s3, d, 64);
    }
    if (ks == 0) {
      float4 h;
      h.x = fast_tanh(s0 + ucur.x);
      h.y = fast_tanh(s1 + ucur.y);
      h.z = fast_tanh(s2 + ucur.z);
      h.w = fast_tanh(s3 + ucur.w);
      *(float4*)&hbuf[cur ^ 1][4 * c0] = h;
    }
    ucur = unext;
    cur ^= 1;
    __syncthreads();
  }
  if (tid < 64)
    *(float4*)(hfinal + (size_t)b * Hn + 4 * tid) =
        *(const float4*)&hbuf[cur][4 * tid];
}

// ---------------------------------------------------------------------------
// Phase 4: out = softmax(h2_T @ Wd + bd). One WG (128 thr) per batch row.
// ---------------------------------------------------------------------------
__global__ __launch_bounds__(128) void head_kernel(
    const float* __restrict__ hfinal,  // [B,256]
    const float* __restrict__ Wd,      // [256,128]
    const float* __restrict__ bd,      // [128]
    float* __restrict__ out) {         // [B,128]
  __shared__ float hrow[Hn];
  __shared__ float red[On];
  const int o = threadIdx.x;
  const int b = blockIdx.x;
  hrow[o] = hfinal[(size_t)b * Hn + o];
  hrow[o + 128] = hfinal[(size_t)b * Hn + 128 + o];
  __syncthreads();
  float acc = bd[o];
  #pragma unroll 8
  for (int k = 0; k < Hn; ++k) acc = fmaf(hrow[k], Wd[(size_t)k * On + o], acc);
  red[o] = acc;
  __syncthreads();
  #pragma unroll
  for (int s = 64; s > 0; s >>= 1) {
    if (o < s) red[o] = fmaxf(red[o], red[o + s]);
    __syncthreads();
  }
  const float mx = red[0];
  __syncthreads();
  const float e = __expf(acc - mx);
  red[o] = e;
  __syncthreads();
  #pragma unroll
  for (int s = 64; s > 0; s >>= 1) {
    if (o < s) red[o] += red[o + s];
    __syncthreads();
  }
  out[(size_t)b * On + o] = e / red[0];
}

// ---------------------------------------------------------------------------
extern "C" void kernel_launch(void* const* d_in, const int* in_sizes, int n_in,
                              void* d_out, int out_size, void* d_ws, size_t ws_size,
                              hipStream_t stream) {
  const float* x   = (const float*)d_in[0];
  const float* Wx1 = (const float*)d_in[1];
  const float* Wh1 = (const float*)d_in[2];
  const float* b1  = (const float*)d_in[3];
  const float* Wx2 = (const float*)d_in[4];
  const float* Wh2 = (const float*)d_in[5];
  const float* b2  = (const float*)d_in[6];
  const float* Wd  = (const float*)d_in[7];
  const float* bd  = (const float*)d_in[8];
  float* out = (float*)d_out;

  // Workspace: one [B*T*256] f32 buffer (h1, overwritten in place by u2) + h2 final.
  float* buf = (float*)d_ws;
  float* hfinal = buf + (size_t)Bn * Tn * Hn;

  scan1_kernel<<<Bn, 512, 0, stream>>>(x, Wx1, Wh1, b1, buf);
  gemm256_kernel<<<(Bn * Tn) / 64, 256, 0, stream>>>(buf, Wx2, b2, buf, Bn * Tn);
  scan2_kernel<<<Bn, 512, 0, stream>>>(buf, Wh2, hfinal);
  head_kernel<<<Bn, 128, 0, stream>>>(hfinal, Wd, bd, out);
}

// Round 3
// 2297.665 us; speedup vs baseline: 1.1467x; 1.1000x over previous
//
#include <hip/hip_runtime.h>
#include <cstdint>

constexpr int Bn = 128;
constexpr int Tn = 1024;
constexpr int Dn = 64;
constexpr int Hn = 256;   // H1 == H2 == 256
constexpr int On = 128;
constexpr int SLICE = 36; // padded LDS stride per 32-float K-slice (kills 8-way conflicts)

typedef float v2f __attribute__((ext_vector_type(2)));

__device__ __forceinline__ float fast_tanh(float x) {
  float e = __expf(2.0f * x);
  return 1.0f - 2.0f / (e + 1.0f);
}

// h element e lives at hbuf[(e>>5)*SLICE + (e&31)]; slice ks = elements [32ks,32ks+32)
__device__ __forceinline__ int hb_base(int c0) { return (c0 >> 3) * SLICE + 4 * (c0 & 7); }

// ---------------------------------------------------------------------------
// Phase 1: per-batch layer-1 scan. One WG (512 thr) per batch element.
// Thread (c0=tid>>3, ks=tid&7): columns [4c0,4c0+4), K-slice ks (32 Wh rows +
// 8 Wx rows) in VGPRs as k-paired v2f (v_pk_fma_f32). Padded hbuf layout ->
// conflict-free ds_read_b128. Global x loads and h1 stores batched per 8-step
// block so the vmcnt(0)-before-s_barrier drain fires once per 8 steps.
// ---------------------------------------------------------------------------
__global__ __launch_bounds__(512) void scan1_kernel(
    const float* __restrict__ x,    // [B,T,64]
    const float* __restrict__ Wx1,  // [64,256]
    const float* __restrict__ Wh1,  // [256,256]
    const float* __restrict__ b1,   // [256]
    float* __restrict__ h1out) {    // [B,T,256]
  __shared__ alignas(16) float hbuf[2][8 * SLICE];
  __shared__ alignas(16) float xbuf[2][8][Dn];
  const int tid = threadIdx.x;
  const int c0 = tid >> 3;
  const int ks = tid & 7;
  const int b = blockIdx.x;
  const float* xb = x + (size_t)b * Tn * Dn;
  float* hb = h1out + (size_t)b * Tn * Hn;

  v2f whp[16][4];
  #pragma unroll
  for (int q = 0; q < 16; ++q) {
    const float* r0 = Wh1 + (size_t)(ks * 32 + 2 * q) * Hn + 4 * c0;
    float4 a = *(const float4*)r0;
    float4 bb = *(const float4*)(r0 + Hn);
    whp[q][0] = (v2f){a.x, bb.x};
    whp[q][1] = (v2f){a.y, bb.y};
    whp[q][2] = (v2f){a.z, bb.z};
    whp[q][3] = (v2f){a.w, bb.w};
  }
  v2f wxp[4][4];
  #pragma unroll
  for (int q = 0; q < 4; ++q) {
    const float* r0 = Wx1 + (size_t)(ks * 8 + 2 * q) * Hn + 4 * c0;
    float4 a = *(const float4*)r0;
    float4 bb = *(const float4*)(r0 + Hn);
    wxp[q][0] = (v2f){a.x, bb.x};
    wxp[q][1] = (v2f){a.y, bb.y};
    wxp[q][2] = (v2f){a.z, bb.z};
    wxp[q][3] = (v2f){a.w, bb.w};
  }
  const float4 bias = *(const float4*)(b1 + 4 * c0);

  if (tid < 64) *(float4*)&hbuf[0][hb_base(tid)] = make_float4(0.f, 0.f, 0.f, 0.f);
  xbuf[0][tid >> 6][tid & 63] = xb[tid];  // steps 0..7
  __syncthreads();

  float4 hreg[8];
  int cur = 0;
  for (int t0 = 0; t0 < Tn; t0 += 8) {
    const int xcur = (t0 >> 3) & 1;
    float xn = 0.f;
    if (t0 + 8 < Tn) xn = xb[(size_t)(t0 + 8) * Dn + tid];  // next block, 1 load/thread

    #pragma unroll
    for (int s = 0; s < 8; ++s) {
      v2f a0 = (v2f){0.f, 0.f}, a1 = a0, a2 = a0, a3 = a0;
      const float4* h4 = (const float4*)&hbuf[cur][ks * SLICE];
      #pragma unroll
      for (int qq = 0; qq < 8; ++qq) {
        float4 hv = h4[qq];
        v2f hA = (v2f){hv.x, hv.y};
        v2f hB = (v2f){hv.z, hv.w};
        a0 = __builtin_elementwise_fma(hA, whp[2 * qq][0], a0);
        a1 = __builtin_elementwise_fma(hA, whp[2 * qq][1], a1);
        a2 = __builtin_elementwise_fma(hA, whp[2 * qq][2], a2);
        a3 = __builtin_elementwise_fma(hA, whp[2 * qq][3], a3);
        a0 = __builtin_elementwise_fma(hB, whp[2 * qq + 1][0], a0);
        a1 = __builtin_elementwise_fma(hB, whp[2 * qq + 1][1], a1);
        a2 = __builtin_elementwise_fma(hB, whp[2 * qq + 1][2], a2);
        a3 = __builtin_elementwise_fma(hB, whp[2 * qq + 1][3], a3);
      }
      const float4* x4 = (const float4*)&xbuf[xcur][s][ks * 8];
      #pragma unroll
      for (int qq = 0; qq < 2; ++qq) {
        float4 xv = x4[qq];
        v2f xA = (v2f){xv.x, xv.y};
        v2f xB = (v2f){xv.z, xv.w};
        a0 = __builtin_elementwise_fma(xA, wxp[2 * qq][0], a0);
        a1 = __builtin_elementwise_fma(xA, wxp[2 * qq][1], a1);
        a2 = __builtin_elementwise_fma(xA, wxp[2 * qq][2], a2);
        a3 = __builtin_elementwise_fma(xA, wxp[2 * qq][3], a3);
        a0 = __builtin_elementwise_fma(xB, wxp[2 * qq + 1][0], a0);
        a1 = __builtin_elementwise_fma(xB, wxp[2 * qq + 1][1], a1);
        a2 = __builtin_elementwise_fma(xB, wxp[2 * qq + 1][2], a2);
        a3 = __builtin_elementwise_fma(xB, wxp[2 * qq + 1][3], a3);
      }
      float s0 = a0.x + a0.y;
      float s1 = a1.x + a1.y;
      float s2 = a2.x + a2.y;
      float s3 = a3.x + a3.y;
      #pragma unroll
      for (int d = 1; d < 8; d <<= 1) {
        s0 += __shfl_xor(s0, d, 64);
        s1 += __shfl_xor(s1, d, 64);
        s2 += __shfl_xor(s2, d, 64);
        s3 += __shfl_xor(s3, d, 64);
      }
      if (ks == 0) {
        float4 h;
        h.x = fast_tanh(s0 + bias.x);
        h.y = fast_tanh(s1 + bias.y);
        h.z = fast_tanh(s2 + bias.z);
        h.w = fast_tanh(s3 + bias.w);
        *(float4*)&hbuf[cur ^ 1][hb_base(c0)] = h;
        hreg[s] = h;
      }
      cur ^= 1;
      if (s == 7) {
        xbuf[xcur ^ 1][tid >> 6][tid & 63] = xn;  // stage next block's x
        if (ks == 0) {
          #pragma unroll
          for (int s2 = 0; s2 < 8; ++s2)
            *(float4*)(hb + (size_t)(t0 + s2) * Hn + 4 * c0) = hreg[s2];
        }
      }
      __syncthreads();  // one barrier per step; double-buffered hbuf/xbuf
    }
  }
}

// ---------------------------------------------------------------------------
// Phase 2: u2 = h1 @ Wx2 + b2.  M=131072, N=K=256.  WG = 64 rows x 256 cols.
// In-place safe: each WG finishes all reads of its 64 rows before epilogue.
// ---------------------------------------------------------------------------
__global__ __launch_bounds__(256) void gemm256_kernel(
    const float* A,                 // [M,256] (may alias out)
    const float* __restrict__ W,    // [256,256]
    const float* __restrict__ bias, // [256]
    float* out,                     // [M,256]
    int M) {
  __shared__ alignas(16) float At[64][64];  // 16 KB
  const int j = threadIdx.x;
  const int m0 = blockIdx.x * 64;
  float acc[64];
  #pragma unroll
  for (int m = 0; m < 64; ++m) acc[m] = 0.f;

  for (int kc = 0; kc < 256; kc += 64) {
    __syncthreads();
    {
      const int flat = j * 16;
      const int row = flat >> 6;
      const int kk = flat & 63;
      const float* src = A + (size_t)(m0 + row) * 256 + kc + kk;
      float4 v0 = ((const float4*)src)[0];
      float4 v1 = ((const float4*)src)[1];
      float4 v2 = ((const float4*)src)[2];
      float4 v3 = ((const float4*)src)[3];
      *(float4*)&At[row][kk + 0] = v0;
      *(float4*)&At[row][kk + 4] = v1;
      *(float4*)&At[row][kk + 8] = v2;
      *(float4*)&At[row][kk + 12] = v3;
    }
    __syncthreads();
    const float* Wp = W + (size_t)kc * 256 + j;
    for (int kq = 0; kq < 16; ++kq) {
      float w0 = Wp[(size_t)(4 * kq + 0) * 256];
      float w1 = Wp[(size_t)(4 * kq + 1) * 256];
      float w2 = Wp[(size_t)(4 * kq + 2) * 256];
      float w3 = Wp[(size_t)(4 * kq + 3) * 256];
      #pragma unroll
      for (int m = 0; m < 64; ++m) {
        float4 a = *(const float4*)&At[m][4 * kq];  // broadcast read
        acc[m] = fmaf(a.x, w0, acc[m]);
        acc[m] = fmaf(a.y, w1, acc[m]);
        acc[m] = fmaf(a.z, w2, acc[m]);
        acc[m] = fmaf(a.w, w3, acc[m]);
      }
    }
  }
  const float bj = bias[j];
  #pragma unroll
  for (int m = 0; m < 64; ++m)
    out[(size_t)(m0 + m) * 256 + j] = acc[m] + bj;
}

// ---------------------------------------------------------------------------
// Phase 3: per-batch layer-2 scan, same structure as scan1.
// U loads batched: ks==0 lanes hold 8-step ping-pong float4 registers,
// prefetched one block ahead (no per-step global load, 1 drain / 8 steps).
// ---------------------------------------------------------------------------
__global__ __launch_bounds__(512) void scan2_kernel(
    const float* __restrict__ U,    // [B,T,256] = h1@Wx2 + b2
    const float* __restrict__ Wh2,  // [256,256]
    float* __restrict__ hfinal) {   // [B,256]
  __shared__ alignas(16) float hbuf[2][8 * SLICE];
  const int tid = threadIdx.x;
  const int c0 = tid >> 3;
  const int ks = tid & 7;
  const int b = blockIdx.x;
  const float* Ub = U + (size_t)b * Tn * Hn;

  v2f whp[16][4];
  #pragma unroll
  for (int q = 0; q < 16; ++q) {
    const float* r0 = Wh2 + (size_t)(ks * 32 + 2 * q) * Hn + 4 * c0;
    float4 a = *(const float4*)r0;
    float4 bb = *(const float4*)(r0 + Hn);
    whp[q][0] = (v2f){a.x, bb.x};
    whp[q][1] = (v2f){a.y, bb.y};
    whp[q][2] = (v2f){a.z, bb.z};
    whp[q][3] = (v2f){a.w, bb.w};
  }

  if (tid < 64) *(float4*)&hbuf[0][hb_base(tid)] = make_float4(0.f, 0.f, 0.f, 0.f);
  __syncthreads();

  float4 ucur[8], unxt[8];
  if (ks == 0) {
    #pragma unroll
    for (int s = 0; s < 8; ++s)
      ucur[s] = *(const float4*)(Ub + (size_t)s * Hn + 4 * c0);
  }

  int cur = 0;
  for (int t0 = 0; t0 < Tn; t0 += 8) {
    if (ks == 0 && t0 + 8 < Tn) {
      #pragma unroll
      for (int s = 0; s < 8; ++s)
        unxt[s] = *(const float4*)(Ub + (size_t)(t0 + 8 + s) * Hn + 4 * c0);
    }
    #pragma unroll
    for (int s = 0; s < 8; ++s) {
      v2f a0 = (v2f){0.f, 0.f}, a1 = a0, a2 = a0, a3 = a0;
      const float4* h4 = (const float4*)&hbuf[cur][ks * SLICE];
      #pragma unroll
      for (int qq = 0; qq < 8; ++qq) {
        float4 hv = h4[qq];
        v2f hA = (v2f){hv.x, hv.y};
        v2f hB = (v2f){hv.z, hv.w};
        a0 = __builtin_elementwise_fma(hA, whp[2 * qq][0], a0);
        a1 = __builtin_elementwise_fma(hA, whp[2 * qq][1], a1);
        a2 = __builtin_elementwise_fma(hA, whp[2 * qq][2], a2);
        a3 = __builtin_elementwise_fma(hA, whp[2 * qq][3], a3);
        a0 = __builtin_elementwise_fma(hB, whp[2 * qq + 1][0], a0);
        a1 = __builtin_elementwise_fma(hB, whp[2 * qq + 1][1], a1);
        a2 = __builtin_elementwise_fma(hB, whp[2 * qq + 1][2], a2);
        a3 = __builtin_elementwise_fma(hB, whp[2 * qq + 1][3], a3);
      }
      float s0 = a0.x + a0.y;
      float s1 = a1.x + a1.y;
      float s2 = a2.x + a2.y;
      float s3 = a3.x + a3.y;
      #pragma unroll
      for (int d = 1; d < 8; d <<= 1) {
        s0 += __shfl_xor(s0, d, 64);
        s1 += __shfl_xor(s1, d, 64);
        s2 += __shfl_xor(s2, d, 64);
        s3 += __shfl_xor(s3, d, 64);
      }
      if (ks == 0) {
        float4 h;
        h.x = fast_tanh(s0 + ucur[s].x);
        h.y = fast_tanh(s1 + ucur[s].y);
        h.z = fast_tanh(s2 + ucur[s].z);
        h.w = fast_tanh(s3 + ucur[s].w);
        *(float4*)&hbuf[cur ^ 1][hb_base(c0)] = h;
      }
      cur ^= 1;
      __syncthreads();
    }
    if (ks == 0) {
      #pragma unroll
      for (int s = 0; s < 8; ++s) ucur[s] = unxt[s];
    }
  }
  if (tid < 64)
    *(float4*)(hfinal + (size_t)b * Hn + 4 * tid) =
        *(const float4*)&hbuf[cur][hb_base(tid)];
}

// ---------------------------------------------------------------------------
// Phase 4: out = softmax(h2_T @ Wd + bd). One WG (128 thr) per batch row.
// ---------------------------------------------------------------------------
__global__ __launch_bounds__(128) void head_kernel(
    const float* __restrict__ hfinal,  // [B,256]
    const float* __restrict__ Wd,      // [256,128]
    const float* __restrict__ bd,      // [128]
    float* __restrict__ out) {         // [B,128]
  __shared__ float hrow[Hn];
  __shared__ float red[On];
  const int o = threadIdx.x;
  const int b = blockIdx.x;
  hrow[o] = hfinal[(size_t)b * Hn + o];
  hrow[o + 128] = hfinal[(size_t)b * Hn + 128 + o];
  __syncthreads();
  float acc = bd[o];
  #pragma unroll 8
  for (int k = 0; k < Hn; ++k) acc = fmaf(hrow[k], Wd[(size_t)k * On + o], acc);
  red[o] = acc;
  __syncthreads();
  #pragma unroll
  for (int s = 64; s > 0; s >>= 1) {
    if (o < s) red[o] = fmaxf(red[o], red[o + s]);
    __syncthreads();
  }
  const float mx = red[0];
  __syncthreads();
  const float e = __expf(acc - mx);
  red[o] = e;
  __syncthreads();
  #pragma unroll
  for (int s = 64; s > 0; s >>= 1) {
    if (o < s) red[o] += red[o + s];
    __syncthreads();
  }
  out[(size_t)b * On + o] = e / red[0];
}

// ---------------------------------------------------------------------------
extern "C" void kernel_launch(void* const* d_in, const int* in_sizes, int n_in,
                              void* d_out, int out_size, void* d_ws, size_t ws_size,
                              hipStream_t stream) {
  const float* x   = (const float*)d_in[0];
  const float* Wx1 = (const float*)d_in[1];
  const float* Wh1 = (const float*)d_in[2];
  const float* b1  = (const float*)d_in[3];
  const float* Wx2 = (const float*)d_in[4];
  const float* Wh2 = (const float*)d_in[5];
  const float* b2  = (const float*)d_in[6];
  const float* Wd  = (const float*)d_in[7];
  const float* bd  = (const float*)d_in[8];
  float* out = (float*)d_out;

  float* buf = (float*)d_ws;                     // h1 then (in-place) u2: [B*T*256]
  float* hfinal = buf + (size_t)Bn * Tn * Hn;    // [B*256]

  scan1_kernel<<<Bn, 512, 0, stream>>>(x, Wx1, Wh1, b1, buf);
  gemm256_kernel<<<(Bn * Tn) / 64, 256, 0, stream>>>(buf, Wx2, b2, buf, Bn * Tn);
  scan2_kernel<<<Bn, 512, 0, stream>>>(buf, Wh2, hfinal);
  head_kernel<<<Bn, 128, 0, stream>>>(hfinal, Wd, bd, out);
}